// Round 1
// baseline (741.638 us; speedup 1.0000x reference)
//
#include <hip/hip_runtime.h>
#include <math.h>

// RC thermal scan: t_{s+1} = a*t_s + c_s, a = 1 - DT/(R*C) (constant),
// c_s = (DT/C) * (t_out/R - g*u + A_eff*so).
// One block per batch row (S=4096), 256 threads x 16 steps each.
// Parallel affine scan: per-thread local fold -> LDS Hillis-Steele scan of
// (m, d) pairs -> replay with exclusive prefix.

#define SLEN 4096
#define THREADS 256
#define PER 16  // SLEN / THREADS

__global__ __launch_bounds__(THREADS) void rc_scan_kernel(
    const float* __restrict__ in,
    const float* __restrict__ rawR,
    const float* __restrict__ rawC,
    const float* __restrict__ rawA,
    const float* __restrict__ rawG,
    float* __restrict__ out)
{
    __shared__ float sm_m[THREADS];
    __shared__ float sm_d[THREADS];

    const int row = blockIdx.x;
    const int tid = threadIdx.x;

    // Bounded params (cheap, every thread computes)
    const float sR = 1.0f / (1.0f + expf(-rawR[0]));
    const float sC = 1.0f / (1.0f + expf(-rawC[0]));
    const float sA = 1.0f / (1.0f + expf(-rawA[0]));
    const float sG = 1.0f / (1.0f + expf(-rawG[0]));
    const float R = 0.0001f + (0.2f - 0.0001f) * sR;
    const float C = 100000.0f + (100000000.0f - 100000.0f) * sC;
    const float A = 0.2f * sA;
    const float g = 1.0f + (20000.0f - 1.0f) * sG;

    const float k     = 900.0f / C;      // DT / C
    const float kinvR = k / R;
    const float a     = 1.0f - kinvR;    // constant multiplier
    const float kg    = k * g;
    const float kA    = k * A;

    const float4* rowp = (const float4*)(in + (size_t)row * (size_t)SLEN * 4);

    // t0 = t_in[row, 0] (channel 0 of step 0) — broadcast read
    const float t0 = rowp[0].x;

    // Load 16 steps, compute c_j in registers
    float c[PER];
#pragma unroll
    for (int j = 0; j < PER; ++j) {
        float4 v = rowp[tid * PER + j];
        c[j] = kinvR * v.y - kg * v.z + kA * v.w;
    }

    // Local affine fold: t_end = a^16 * t_start + d
    float d = 0.0f;
#pragma unroll
    for (int j = 0; j < PER; ++j) d = a * d + c[j];
    const float a2 = a * a, a4 = a2 * a2, a8 = a4 * a4;
    const float m16 = a8 * a8;  // a^16

    // Inclusive Hillis-Steele scan of affine pairs across 256 threads.
    // Compose left-then-right: (ml,dl) then (mr,dr) => (ml*mr, mr*dl + dr)
    float cm = m16, cd = d;
    sm_m[tid] = cm;
    sm_d[tid] = cd;
    __syncthreads();
    for (int off = 1; off < THREADS; off <<= 1) {
        float pm = 1.0f, pd = 0.0f;
        const bool has = (tid >= off);
        if (has) { pm = sm_m[tid - off]; pd = sm_d[tid - off]; }
        __syncthreads();
        if (has) { cd = cm * pd + cd; cm = pm * cm; }
        sm_m[tid] = cm;
        sm_d[tid] = cd;
        __syncthreads();
    }

    // Exclusive prefix -> starting temperature for this thread's chunk
    float t;
    if (tid == 0) t = t0;
    else          t = sm_m[tid - 1] * t0 + sm_d[tid - 1];

    // Replay 16 steps, stage in registers
    float os[PER];
#pragma unroll
    for (int j = 0; j < PER; ++j) {
        t = a * t + c[j];
        os[j] = t;
    }

    // Vectorized store: 16 contiguous floats per thread
    float4* outp = (float4*)(out + (size_t)row * SLEN + (size_t)tid * PER);
#pragma unroll
    for (int q = 0; q < PER / 4; ++q) {
        outp[q] = make_float4(os[4 * q + 0], os[4 * q + 1],
                              os[4 * q + 2], os[4 * q + 3]);
    }
}

extern "C" void kernel_launch(void* const* d_in, const int* in_sizes, int n_in,
                              void* d_out, int out_size, void* d_ws, size_t ws_size,
                              hipStream_t stream) {
    const float* in   = (const float*)d_in[0];
    const float* rawR = (const float*)d_in[1];
    const float* rawC = (const float*)d_in[2];
    const float* rawA = (const float*)d_in[3];
    const float* rawG = (const float*)d_in[4];
    float* out = (float*)d_out;

    const int B = in_sizes[0] / (SLEN * 4);  // 8192
    rc_scan_kernel<<<dim3(B), dim3(THREADS), 0, stream>>>(
        in, rawR, rawC, rawA, rawG, out);
}

// Round 2
// 719.359 us; speedup vs baseline: 1.0310x; 1.0310x over previous
//
#include <hip/hip_runtime.h>
#include <math.h>

// RC thermal scan: t_{s+1} = a*t_s + c_s, a = 1 - DT/(R*C) (constant),
// c_s = (DT/C) * (t_out/R - g*u + A_eff*so).
// One block per batch row (S=4096), 256 threads.
// R2: decouple memory layout (lane-contiguous, coalesced) from scan layout
// (thread-contiguous) via padded-LDS transpose. R1's direct per-thread
// contiguous global accesses had a 256 B inter-lane stride (64 cache lines
// per instruction) -> ~7x VMEM throughput loss.

#define SLEN 4096
#define THREADS 256
#define PER 16  // SLEN / THREADS
// +1 float of padding per 16 -> breaks the stride-16 bank aliasing
#define PAD_IDX(s) ((((s) >> 4) * 17) + ((s) & 15))

__global__ __launch_bounds__(THREADS) void rc_scan_kernel(
    const float* __restrict__ in,
    const float* __restrict__ rawR,
    const float* __restrict__ rawC,
    const float* __restrict__ rawA,
    const float* __restrict__ rawG,
    float* __restrict__ out)
{
    __shared__ float sm_c[256 * 17];  // 17408 B padded staging
    __shared__ float sm_m[THREADS];
    __shared__ float sm_d[THREADS];

    const int row = blockIdx.x;
    const int tid = threadIdx.x;

    // Bounded params (cheap, every thread computes)
    const float sR = 1.0f / (1.0f + expf(-rawR[0]));
    const float sC = 1.0f / (1.0f + expf(-rawC[0]));
    const float sA = 1.0f / (1.0f + expf(-rawA[0]));
    const float sG = 1.0f / (1.0f + expf(-rawG[0]));
    const float R = 0.0001f + (0.2f - 0.0001f) * sR;
    const float C = 100000.0f + (100000000.0f - 100000.0f) * sC;
    const float A = 0.2f * sA;
    const float g = 1.0f + (20000.0f - 1.0f) * sG;

    const float k     = 900.0f / C;      // DT / C
    const float kinvR = k / R;
    const float a     = 1.0f - kinvR;    // constant multiplier
    const float kg    = k * g;
    const float kA    = k * A;

    const float4* rowp = (const float4*)(in + (size_t)row * (size_t)SLEN * 4);

    // t0 = t_in[row, 0] — broadcast read (same address all lanes, cached)
    const float t0 = rowp[0].x;

    // Phase 1: coalesced load (lane i -> base + i*16B), reduce to c_s, stage
    // into padded LDS.
#pragma unroll
    for (int q = 0; q < PER; ++q) {
        const int s = tid + THREADS * q;
        float4 v = rowp[s];
        sm_c[PAD_IDX(s)] = kinvR * v.y - kg * v.z + kA * v.w;
    }
    __syncthreads();

    // Phase 2: gather this thread's 16 contiguous c into registers.
    // addr = tid*17 + j -> conflict-free (stride 17 across lanes).
    float c[PER];
#pragma unroll
    for (int j = 0; j < PER; ++j) c[j] = sm_c[tid * 17 + j];

    // Local affine fold: t_end = a^16 * t_start + d
    float d = 0.0f;
#pragma unroll
    for (int j = 0; j < PER; ++j) d = fmaf(a, d, c[j]);
    const float a2 = a * a, a4 = a2 * a2, a8 = a4 * a4;
    const float m16 = a8 * a8;  // a^16

    // Inclusive Hillis-Steele scan of affine pairs across 256 threads.
    // Compose left-then-right: (ml,dl) then (mr,dr) => (ml*mr, mr*dl + dr)
    float cm = m16, cd = d;
    sm_m[tid] = cm;
    sm_d[tid] = cd;
    __syncthreads();
    for (int off = 1; off < THREADS; off <<= 1) {
        float pm = 1.0f, pd = 0.0f;
        const bool has = (tid >= off);
        if (has) { pm = sm_m[tid - off]; pd = sm_d[tid - off]; }
        __syncthreads();
        if (has) { cd = fmaf(cm, pd, cd); cm = pm * cm; }
        sm_m[tid] = cm;
        sm_d[tid] = cd;
        __syncthreads();
    }

    // Exclusive prefix -> starting temperature for this thread's chunk
    float t;
    if (tid == 0) t = t0;
    else          t = fmaf(sm_m[tid - 1], t0, sm_d[tid - 1]);

    // Phase 3: replay 16 steps in place (c[j] becomes the output value).
    // Safe to overwrite sm_c[tid*17+j] without a sync: only this thread read
    // those addresses, and the scan's syncthreads ordered phase-1 writes.
#pragma unroll
    for (int j = 0; j < PER; ++j) {
        t = fmaf(a, t, c[j]);
        sm_c[tid * 17 + j] = t;
    }
    __syncthreads();

    // Phase 4: coalesced float4 stores. Lane t stores steps q*1024 + 4t .. +3.
    float* orow = out + (size_t)row * SLEN;
#pragma unroll
    for (int q = 0; q < 4; ++q) {
        const int s0 = q * 1024 + 4 * tid;
        float4 v;
        v.x = sm_c[PAD_IDX(s0 + 0)];
        v.y = sm_c[PAD_IDX(s0 + 1)];
        v.z = sm_c[PAD_IDX(s0 + 2)];
        v.w = sm_c[PAD_IDX(s0 + 3)];
        *(float4*)(orow + s0) = v;
    }
}

extern "C" void kernel_launch(void* const* d_in, const int* in_sizes, int n_in,
                              void* d_out, int out_size, void* d_ws, size_t ws_size,
                              hipStream_t stream) {
    const float* in   = (const float*)d_in[0];
    const float* rawR = (const float*)d_in[1];
    const float* rawC = (const float*)d_in[2];
    const float* rawA = (const float*)d_in[3];
    const float* rawG = (const float*)d_in[4];
    float* out = (float*)d_out;

    const int B = in_sizes[0] / (SLEN * 4);  // 8192
    rc_scan_kernel<<<dim3(B), dim3(THREADS), 0, stream>>>(
        in, rawR, rawC, rawA, rawG, out);
}